// Round 8
// baseline (189.645 us; speedup 1.0000x reference)
//
#include <hip/hip_runtime.h>
#include <hip/hip_bf16.h>

#define Bsz  4096
#define Tn   256
#define CIN  16
#define NCLS 10
#define MB   16          // full 16-row MFMA tile per block

typedef __attribute__((ext_vector_type(8))) short short8;
typedef __attribute__((ext_vector_type(4))) float f32x4;

#if __has_builtin(__builtin_amdgcn_exp2f)
#define EXP2F(x) __builtin_amdgcn_exp2f(x)
#else
#define EXP2F(x) exp2f(x)
#endif
#define RCPF(x) __builtin_amdgcn_rcpf(x)

#define LOG2E 1.442695041f
#define LN2   0.6931471806f

// LDS-only barrier: order LDS writes/reads across waves WITHOUT draining
// vmcnt (global x loads + output stores stay in flight across steps).
#define BARRIER_LDS() do {                                     \
    asm volatile("s_waitcnt lgkmcnt(0)" ::: "memory");         \
    __builtin_amdgcn_s_barrier();                              \
} while (0)

__device__ inline ushort f2bf(float f) {
    union { float f; unsigned u; } x; x.f = f;
    return (ushort)((x.u + 0x7FFF + ((x.u >> 16) & 1)) >> 16);  // RNE
}

// LSTM cell activation: all scales pre-folded (i,f,o: -log2e; g: +2*log2e).
// 7 trans: 4 exp2 + rcp + exp2 + rcp.
__device__ inline float cell_act(float& c, float ai, float af, float ao, float ag) {
    const float ei = EXP2F(ai);
    const float ef = EXP2F(af);
    const float eo = EXP2F(ao);
    const float eg = EXP2F(ag);
    const float A  = 1.f + ei, Bv = 1.f + ef;
    const float G1 = eg + 1.f, G2 = eg - 1.f, O = 1.f + eo;
    const float t0  = A * G1;
    const float num = c * t0 + G2 * Bv;
    const float den = Bv * t0;
    const float cn  = num * RCPF(den);
    c = cn;
    const float e2 = EXP2F(2.f * LOG2E * cn);
    return (e2 - 1.f) * RCPF((e2 + 1.f) * O);
}

// 8 waves, 2/SIMD. Waves 0-3 (A/gate, ub=wave): 12 gate MFMA, transfer acc
// j=2,3 via LDS, activations j=0,1. Waves 4-7 (B/head, hw=wave-4): head MFMA +
// softmax(t-1) + x prefetch, then (after mid-step barrier) activations j=2,3
// from the transferred accs. cst j01 lives in A, j23 in B. 2 LDS barriers/step.
__global__ __launch_bounds__(512, 2) void dualrnn_fused(
    const float* __restrict__ x,  const float* __restrict__ Wl, const float* __restrict__ bl,
    const float* __restrict__ Wc, const float* __restrict__ bc,
    const float* __restrict__ Wd, const float* __restrict__ bd,
    float* __restrict__ out)
{
    // comb: [parity][batch_row][k]; k: 0..15 x, 16..79 h, 80..95 pad(0)
    __shared__ alignas(16) ushort comb[2][16][104];
    __shared__ alignas(16) float accT[4][2][64][4];   // [ub][jj][slot][gate] 8KB
    const int tid  = threadIdx.x;
    const int wave = tid >> 6;
    const int lane = tid & 63;
    const int col  = lane & 15;
    const int grp  = lane >> 4;
    const int b0   = blockIdx.x * MB;
    const bool gatew = (wave < 4);
    const int slot = grp * 16 + col;

    for (int i = tid; i < 2 * 16 * 104; i += 512) ((ushort*)comb)[i] = 0;

    // ---- preload weights (role-specific, loop-invariant in VGPRs) ----
    short8 wf[4][3]; f32x4 biasv[4];
    short8 wcd[2];   f32x4 bcdv;
    if (gatew) {
#pragma unroll
        for (int g = 0; g < 4; ++g) {
            const float sc = (g == 3) ? 2.f * LOG2E : -LOG2E;
            const int R = g * 64 + wave * 16 + col;
            const float bv = bl[R] * sc;
            biasv[g] = (f32x4){bv, bv, bv, bv};
#pragma unroll
            for (int kt = 0; kt < 3; ++kt)
#pragma unroll
                for (int i = 0; i < 8; ++i) {
                    const int k = kt * 32 + grp * 8 + i;
                    wf[g][kt][i] = (short)f2bf(k < 80 ? Wl[R * 80 + k] * sc : 0.f);
                }
        }
    } else {
        // class lanes (col<10): fold +log2e (softmax exp2 merge); dec lane: -log2e.
#pragma unroll
        for (int kt = 0; kt < 2; ++kt)
#pragma unroll
            for (int i = 0; i < 8; ++i) {
                const int k = kt * 32 + grp * 8 + i;
                float v = 0.f;
                if (col < 10)       v = Wc[col * 64 + k] * LOG2E;
                else if (col == 10) v = Wd[k] * -LOG2E;
                wcd[kt][i] = (short)f2bf(v);
            }
        const float bv = (col < 10) ? bc[col] * LOG2E
                       : ((col == 10) ? bd[0] * -LOG2E : 0.f);
        bcdv = (f32x4){bv, bv, bv, bv};
    }

    __syncthreads();   // zeroing done before x_0 write

    if (tid < 256) {   // x_0 into comb[0]; h-section stays zero
        const int r = tid >> 4, ch = tid & 15;
        comb[0][r][ch] = f2bf(x[((size_t)(b0 + r) * Tn) * CIN + ch]);
    }
    __syncthreads();

    float cst[2] = {0, 0};   // A: c state j=0,1 ; B: c state j=2,3
    float pnd = 1.f;         // B, lanes col==10, row grp*4+hw

    const int hw  = wave & 3;            // head-wave id 0..3
    const int row = grp * 4 + hw;        // output row this head thread owns
    float* lp_p = out + ((size_t)(b0 + row) * Tn) * NCLS + col;              // [B][T][10]
    float* pt_p = out + (size_t)Bsz * Tn * NCLS + (size_t)(b0 + row) * Tn;   // [B][T]
    const int t2 = hw * 64 + lane;       // 0..255 across head waves
    const int xr = t2 >> 4, xc = t2 & 15;
    float xva = 0.f;                     // x_{t+1}, written this iter
    const float* xp = x + ((size_t)(b0 + xr) * Tn + 2) * CIN + xc;
    if (!gatew) xva = x[((size_t)(b0 + xr) * Tn + 1) * CIN + xc];

    for (int t = 0; t < Tn; ++t) {
        const ushort (*rdb)[104] = comb[t & 1];
        ushort (*wrb)[104] = comb[(t + 1) & 1];
        if (gatew) {
            const int ub = wave;
            const short8 a0 = *(const short8*)&rdb[col][ 0 + grp * 8];
            const short8 a1 = *(const short8*)&rdb[col][32 + grp * 8];
            const short8 a2 = *(const short8*)&rdb[col][64 + grp * 8];
            f32x4 acc[4];
#pragma unroll
            for (int g = 0; g < 4; ++g) {
                f32x4 z = biasv[g];
                z = __builtin_amdgcn_mfma_f32_16x16x32_bf16(a0, wf[g][0], z, 0, 0, 0);
                z = __builtin_amdgcn_mfma_f32_16x16x32_bf16(a1, wf[g][1], z, 0, 0, 0);
                z = __builtin_amdgcn_mfma_f32_16x16x32_bf16(a2, wf[g][2], z, 0, 0, 0);
                acc[g] = z;
            }
            // transfer acc j=2,3 to head waves (conflict-free b128)
#pragma unroll
            for (int jj = 0; jj < 2; ++jj) {
                f32x4 tv = {acc[0][jj + 2], acc[1][jj + 2], acc[2][jj + 2], acc[3][jj + 2]};
                *(f32x4*)&accT[ub][jj][slot][0] = tv;
            }
            BARRIER_LDS();   // barrier2: transfer visible
            const int hc = 16 + ub * 16 + col;
#pragma unroll
            for (int jj = 0; jj < 2; ++jj) {
                const float h = cell_act(cst[jj], acc[0][jj], acc[1][jj],
                                         acc[2][jj], acc[3][jj]);
                wrb[grp * 4 + jj][hc] = f2bf(h);
            }
        } else {
            // phase 1: x prefetch, head MFMA on h_{t-1}, softmax for step t-1
            float xvn = 0.f;
            if (t + 2 < Tn) xvn = *xp;
            xp += CIN;
            const short8 ha0 = *(const short8*)&rdb[col][16 + grp * 8];
            const short8 ha1 = *(const short8*)&rdb[col][48 + grp * 8];
            f32x4 cz = bcdv;
            cz = __builtin_amdgcn_mfma_f32_16x16x32_bf16(ha0, wcd[0], cz, 0, 0, 0);
            cz = __builtin_amdgcn_mfma_f32_16x16x32_bf16(ha1, wcd[1], cz, 0, 0, 0);
            if (t + 1 < Tn) wrb[xr][xc] = f2bf(xva);   // x_{t+1}, loaded LAST iter
            xva = xvn;
            if (t > 0) {
                // v pre-scaled: col<10 = logit*log2e ; col==10 = -dec_logit*log2e
                float v = (hw & 1) ? ((hw & 2) ? cz[3] : cz[1])
                                   : ((hw & 2) ? cz[2] : cz[0]);
                const float e = EXP2F(v);              // one exp2 serves both
                float s = (col < 10) ? e : 0.f;
                s += __int_as_float(__builtin_amdgcn_ds_swizzle(__float_as_int(s), 0x041F));
                s += __int_as_float(__builtin_amdgcn_ds_swizzle(__float_as_int(s), 0x081F));
                s += __int_as_float(__builtin_amdgcn_ds_swizzle(__float_as_int(s), 0x101F));
                s += __int_as_float(__builtin_amdgcn_ds_swizzle(__float_as_int(s), 0x201F));
                const float lse = __logf(s);
                if (col < 10) {
                    lp_p[0] = v * LN2 - lse;           // natural log-softmax
                } else if (col == 10) {
                    const float d = RCPF(1.f + e);     // sigmoid(dec)
                    pt_p[0] = d * pnd;
                    pnd *= (1.f - d);
                }
                lp_p += NCLS;
                pt_p += 1;
            }
            BARRIER_LDS();   // barrier2: acc transfer ready
            // phase 2: activations j=2,3 from transferred accs
            const int hc = 16 + hw * 16 + col;
#pragma unroll
            for (int jj = 0; jj < 2; ++jj) {
                const f32x4 tv = *(const f32x4*)&accT[hw][jj][slot][0];
                const float h = cell_act(cst[jj], tv[0], tv[1], tv[2], tv[3]);
                wrb[grp * 4 + 2 + jj][hc] = f2bf(h);
            }
        }
        BARRIER_LDS();       // barrier1: h_t (+x_{t+1}) complete
    }

    // epilogue: output step Tn-1 from h_{Tn-1} in comb[Tn&1] (head waves)
    if (!gatew) {
        const ushort (*rdb)[104] = comb[Tn & 1];
        const short8 ha0 = *(const short8*)&rdb[col][16 + grp * 8];
        const short8 ha1 = *(const short8*)&rdb[col][48 + grp * 8];
        f32x4 cz = bcdv;
        cz = __builtin_amdgcn_mfma_f32_16x16x32_bf16(ha0, wcd[0], cz, 0, 0, 0);
        cz = __builtin_amdgcn_mfma_f32_16x16x32_bf16(ha1, wcd[1], cz, 0, 0, 0);
        float v = (hw & 1) ? ((hw & 2) ? cz[3] : cz[1])
                           : ((hw & 2) ? cz[2] : cz[0]);
        const float e = EXP2F(v);
        float s = (col < 10) ? e : 0.f;
        s += __int_as_float(__builtin_amdgcn_ds_swizzle(__float_as_int(s), 0x041F));
        s += __int_as_float(__builtin_amdgcn_ds_swizzle(__float_as_int(s), 0x081F));
        s += __int_as_float(__builtin_amdgcn_ds_swizzle(__float_as_int(s), 0x101F));
        s += __int_as_float(__builtin_amdgcn_ds_swizzle(__float_as_int(s), 0x201F));
        const float lse = __logf(s);
        if (col < 10)       lp_p[0] = v * LN2 - lse;
        else if (col == 10) pt_p[0] = pnd;   // is_last: Pt = pnd_{T-1}
    }
}

extern "C" void kernel_launch(void* const* d_in, const int* in_sizes, int n_in,
                              void* d_out, int out_size, void* d_ws, size_t ws_size,
                              hipStream_t stream) {
    const float* x  = (const float*)d_in[0];
    const float* Wl = (const float*)d_in[1];
    const float* bl = (const float*)d_in[2];
    const float* Wc = (const float*)d_in[3];
    const float* bc = (const float*)d_in[4];
    const float* Wd = (const float*)d_in[5];
    const float* bd = (const float*)d_in[6];
    float* out = (float*)d_out;

    hipLaunchKernelGGL(dualrnn_fused, dim3(Bsz / MB), dim3(512), 0, stream,
                       x, Wl, bl, Wc, bc, Wd, bd, out);
}

// Round 9
// 147.923 us; speedup vs baseline: 1.2821x; 1.2821x over previous
//
#include <hip/hip_runtime.h>
#include <hip/hip_bf16.h>

#define Bsz  4096
#define Tn   256
#define CIN  16
#define NCLS 10
#define MB   16          // full 16-row MFMA tile per block

typedef __attribute__((ext_vector_type(8))) short short8;
typedef __attribute__((ext_vector_type(4))) float f32x4;

#if __has_builtin(__builtin_amdgcn_exp2f)
#define EXP2F(x) __builtin_amdgcn_exp2f(x)
#else
#define EXP2F(x) exp2f(x)
#endif
#define RCPF(x) __builtin_amdgcn_rcpf(x)

#define LOG2E 1.442695041f
#define LN2   0.6931471806f

// LDS-only barrier: order LDS writes/reads across waves WITHOUT draining
// vmcnt (global x loads + output stores stay in flight across steps).
#define BARRIER_LDS() do {                                     \
    asm volatile("s_waitcnt lgkmcnt(0)" ::: "memory");         \
    __builtin_amdgcn_s_barrier();                              \
} while (0)

__device__ inline ushort f2bf(float f) {
    union { float f; unsigned u; } x; x.f = f;
    return (ushort)((x.u + 0x7FFF + ((x.u >> 16) & 1)) >> 16);  // RNE
}
__device__ inline unsigned cvt_pk_bf16(float lo, float hi) {
    unsigned d;
    asm("v_cvt_pk_bf16_f32 %0, %1, %2" : "=v"(d) : "v"(lo), "v"(hi));
    return d;
}

// 8 waves, 2/SIMD: waves 0-3 gates (SWAPPED operands: A=W so D[m=unit][n=batch]),
// waves 4-7 head (unswapped). One LDS barrier per step.
__global__ __launch_bounds__(512, 2) void dualrnn_fused(
    const float* __restrict__ x,  const float* __restrict__ Wl, const float* __restrict__ bl,
    const float* __restrict__ Wc, const float* __restrict__ bc,
    const float* __restrict__ Wd, const float* __restrict__ bd,
    float* __restrict__ out)
{
    // comb: [parity][batch_row][k]; k: 0..15 x, 16..79 h, 80..95 pad(0)
    __shared__ alignas(16) ushort comb[2][16][104];
    const int tid  = threadIdx.x;
    const int wave = tid >> 6;
    const int lane = tid & 63;
    const int col  = lane & 15;
    const int grp  = lane >> 4;
    const int b0   = blockIdx.x * MB;
    const bool gatew = (wave < 4);

    for (int i = tid; i < 2 * 16 * 104; i += 512) ((ushort*)comb)[i] = 0;

    // ---- preload weights ----
    // gates (swapped): A-fragment lane holds W[g*64 + ub*16 + col][k]; scales
    // folded (i,f,o: -log2e; g: +2*log2e). bias per-j (unit = ub*16+grp*4+j).
    short8 wf[4][3]; f32x4 biasv[4];
    short8 wcd[2];   f32x4 bcdv;
    if (gatew) {
        const int ub = wave;
#pragma unroll
        for (int g = 0; g < 4; ++g) {
            const float sc = (g == 3) ? 2.f * LOG2E : -LOG2E;
#pragma unroll
            for (int j = 0; j < 4; ++j)
                biasv[g][j] = bl[g * 64 + ub * 16 + grp * 4 + j] * sc;
            const int R = g * 64 + ub * 16 + col;
#pragma unroll
            for (int kt = 0; kt < 3; ++kt)
#pragma unroll
                for (int i = 0; i < 8; ++i) {
                    const int k = kt * 32 + grp * 8 + i;
                    wf[g][kt][i] = (short)f2bf(k < 80 ? Wl[R * 80 + k] * sc : 0.f);
                }
        }
    } else {
        // head (unswapped): class lanes fold +log2e; dec lane folds -log2e.
#pragma unroll
        for (int kt = 0; kt < 2; ++kt)
#pragma unroll
            for (int i = 0; i < 8; ++i) {
                const int k = kt * 32 + grp * 8 + i;
                float v = 0.f;
                if (col < 10)       v = Wc[col * 64 + k] * LOG2E;
                else if (col == 10) v = Wd[k] * -LOG2E;
                wcd[kt][i] = (short)f2bf(v);
            }
        const float bv = (col < 10) ? bc[col] * LOG2E
                       : ((col == 10) ? bd[0] * -LOG2E : 0.f);
        bcdv = (f32x4){bv, bv, bv, bv};
    }

    __syncthreads();   // zeroing done before x_0 write

    if (tid < 256) {   // x_0 into comb[0]; h-section stays zero
        const int r = tid >> 4, ch = tid & 15;
        comb[0][r][ch] = f2bf(x[((size_t)(b0 + r) * Tn) * CIN + ch]);
    }
    __syncthreads();

    float cst[4] = {0, 0, 0, 0};  // gates: c[batch=col][unit=ub*16+grp*4+j]
    float pnd = 1.f;              // head, lanes col==10, row grp*4+hw

    const int hw  = wave & 3;            // head-wave id 0..3
    const int row = grp * 4 + hw;        // output row this head thread owns
    float* lp_p = out + ((size_t)(b0 + row) * Tn) * NCLS + col;              // [B][T][10]
    float* pt_p = out + (size_t)Bsz * Tn * NCLS + (size_t)(b0 + row) * Tn;   // [B][T]
    const int t2 = hw * 64 + lane;       // 0..255 across head waves
    const int xr = t2 >> 4, xc = t2 & 15;
    float xva = 0.f;                     // x_{t+1}, written this iter
    const float* xp = x + ((size_t)(b0 + xr) * Tn + 2) * CIN + xc;
    if (!gatew) xva = x[((size_t)(b0 + xr) * Tn + 1) * CIN + xc];

    for (int t = 0; t < Tn; ++t) {
        const ushort (*rdb)[104] = comb[t & 1];
        ushort (*wrb)[104] = comb[(t + 1) & 1];
        if (gatew) {
            const int ub = wave;
            // B-fragments from comb (batch = col, K-contiguous)
            const short8 a0 = *(const short8*)&rdb[col][ 0 + grp * 8];
            const short8 a1 = *(const short8*)&rdb[col][32 + grp * 8];
            const short8 a2 = *(const short8*)&rdb[col][64 + grp * 8];
            f32x4 acc[4];
#pragma unroll
            for (int g = 0; g < 4; ++g) {
                f32x4 z = biasv[g];
                z = __builtin_amdgcn_mfma_f32_16x16x32_bf16(wf[g][0], a0, z, 0, 0, 0);
                z = __builtin_amdgcn_mfma_f32_16x16x32_bf16(wf[g][1], a1, z, 0, 0, 0);
                z = __builtin_amdgcn_mfma_f32_16x16x32_bf16(wf[g][2], a2, z, 0, 0, 0);
                acc[g] = z;
            }
            // 4 cells: units ub*16+grp*4+{0..3}, batch col.
            float num[4], den[4], O_[4];
#pragma unroll
            for (int j = 0; j < 4; ++j) {
                const float ei = EXP2F(acc[0][j]);
                const float ef = EXP2F(acc[1][j]);
                const float eo = EXP2F(acc[2][j]);
                const float eg = EXP2F(acc[3][j]);
                const float A  = 1.f + ei, Bv = 1.f + ef;
                const float G1 = eg + 1.f, G2 = eg - 1.f;
                O_[j] = 1.f + eo;
                const float t0 = A * G1;
                num[j] = cst[j] * t0 + G2 * Bv;
                den[j] = Bv * t0;
            }
            // batch reciprocal #1 (1 rcp for 4 dens)
            float rd[4];
            {
                const float p01 = den[0] * den[1];
                const float p012 = p01 * den[2];
                const float r = RCPF(p012 * den[3]);
                const float r012 = r * den[3];
                rd[3] = r * p012;
                const float r01 = r012 * den[2];
                rd[2] = r012 * p01;
                rd[0] = r01 * den[1];
                rd[1] = r01 * den[0];
            }
            float hn[4], hd[4];
#pragma unroll
            for (int j = 0; j < 4; ++j) {
                const float cn = num[j] * rd[j];
                cst[j] = cn;
                const float e2 = EXP2F(2.f * LOG2E * cn);
                hn[j] = e2 - 1.f;
                hd[j] = (e2 + 1.f) * O_[j];
            }
            // batch reciprocal #2
            float rh[4];
            {
                const float p01 = hd[0] * hd[1];
                const float p012 = p01 * hd[2];
                const float r = RCPF(p012 * hd[3]);
                const float r012 = r * hd[3];
                rh[3] = r * p012;
                const float r01 = r012 * hd[2];
                rh[2] = r012 * p01;
                rh[0] = r01 * hd[1];
                rh[1] = r01 * hd[0];
            }
            // pack 4 consecutive-unit h values -> one ds_write_b64
            const unsigned d0 = cvt_pk_bf16(hn[0] * rh[0], hn[1] * rh[1]);
            const unsigned d1 = cvt_pk_bf16(hn[2] * rh[2], hn[3] * rh[3]);
            *(uint2*)&wrb[col][16 + ub * 16 + grp * 4] = (uint2){d0, d1};
        } else {
            // x prefetch, head MFMA on h_{t-1}, softmax for step t-1
            float xvn = 0.f;
            if (t + 2 < Tn) xvn = *xp;
            xp += CIN;
            const short8 ha0 = *(const short8*)&rdb[col][16 + grp * 8];
            const short8 ha1 = *(const short8*)&rdb[col][48 + grp * 8];
            f32x4 cz = bcdv;
            cz = __builtin_amdgcn_mfma_f32_16x16x32_bf16(ha0, wcd[0], cz, 0, 0, 0);
            cz = __builtin_amdgcn_mfma_f32_16x16x32_bf16(ha1, wcd[1], cz, 0, 0, 0);
            if (t + 1 < Tn) wrb[xr][xc] = f2bf(xva);   // x_{t+1}, loaded LAST iter
            xva = xvn;
            if (t > 0) {
                // v pre-scaled: col<10 = logit*log2e ; col==10 = -dec_logit*log2e
                float v = (hw & 1) ? ((hw & 2) ? cz[3] : cz[1])
                                   : ((hw & 2) ? cz[2] : cz[0]);
                const float e = EXP2F(v);              // one exp2 serves both paths
                float s = (col < 10) ? e : 0.f;
                s += __int_as_float(__builtin_amdgcn_ds_swizzle(__float_as_int(s), 0x041F));
                s += __int_as_float(__builtin_amdgcn_ds_swizzle(__float_as_int(s), 0x081F));
                s += __int_as_float(__builtin_amdgcn_ds_swizzle(__float_as_int(s), 0x101F));
                s += __int_as_float(__builtin_amdgcn_ds_swizzle(__float_as_int(s), 0x201F));
                const float lse = __logf(s);
                if (col < 10) {
                    lp_p[0] = v * LN2 - lse;           // natural log-softmax
                } else if (col == 10) {
                    const float d = RCPF(1.f + e);     // sigmoid(dec)
                    pt_p[0] = d * pnd;
                    pnd *= (1.f - d);
                }
                lp_p += NCLS;
                pt_p += 1;
            }
        }
        BARRIER_LDS();
    }

    // epilogue: output step Tn-1 from h_{Tn-1} in comb[Tn&1] (head waves)
    if (!gatew) {
        const ushort (*rdb)[104] = comb[Tn & 1];
        const short8 ha0 = *(const short8*)&rdb[col][16 + grp * 8];
        const short8 ha1 = *(const short8*)&rdb[col][48 + grp * 8];
        f32x4 cz = bcdv;
        cz = __builtin_amdgcn_mfma_f32_16x16x32_bf16(ha0, wcd[0], cz, 0, 0, 0);
        cz = __builtin_amdgcn_mfma_f32_16x16x32_bf16(ha1, wcd[1], cz, 0, 0, 0);
        float v = (hw & 1) ? ((hw & 2) ? cz[3] : cz[1])
                           : ((hw & 2) ? cz[2] : cz[0]);
        const float e = EXP2F(v);
        float s = (col < 10) ? e : 0.f;
        s += __int_as_float(__builtin_amdgcn_ds_swizzle(__float_as_int(s), 0x041F));
        s += __int_as_float(__builtin_amdgcn_ds_swizzle(__float_as_int(s), 0x081F));
        s += __int_as_float(__builtin_amdgcn_ds_swizzle(__float_as_int(s), 0x101F));
        s += __int_as_float(__builtin_amdgcn_ds_swizzle(__float_as_int(s), 0x201F));
        const float lse = __logf(s);
        if (col < 10)       lp_p[0] = v * LN2 - lse;
        else if (col == 10) pt_p[0] = pnd;   // is_last: Pt = pnd_{T-1}
    }
}

extern "C" void kernel_launch(void* const* d_in, const int* in_sizes, int n_in,
                              void* d_out, int out_size, void* d_ws, size_t ws_size,
                              hipStream_t stream) {
    const float* x  = (const float*)d_in[0];
    const float* Wl = (const float*)d_in[1];
    const float* bl = (const float*)d_in[2];
    const float* Wc = (const float*)d_in[3];
    const float* bc = (const float*)d_in[4];
    const float* Wd = (const float*)d_in[5];
    const float* bd = (const float*)d_in[6];
    float* out = (float*)d_out;

    hipLaunchKernelGGL(dualrnn_fused, dim3(Bsz / MB), dim3(512), 0, stream,
                       x, Wl, bl, Wc, bc, Wd, bd, out);
}